// Round 1
// baseline (289.029 us; speedup 1.0000x reference)
//
#include <hip/hip_runtime.h>

typedef __attribute__((ext_vector_type(8))) short short8;
typedef __attribute__((ext_vector_type(4))) float f32x4;

#define CIN 256
#define OUTC 256
#define HWW 4096
#define IMG_H 64
#define IMG_W 64

__device__ __forceinline__ short f2bf(float f) {
    unsigned u = __float_as_uint(f);
    u += 0x7fffu + ((u >> 16) & 1u);
    return (short)(u >> 16);
}

// ---------------- Kernel A: 27-channel offset conv + transform ----------------
// thread = (oc, pixel). Block = 256 consecutive pixels of one oc.
__global__ __launch_bounds__(256) void offs_kernel(
        const float* __restrict__ x, const float* __restrict__ w_off,
        const float* __restrict__ b_off, float* __restrict__ offY,
        float* __restrict__ offX, float* __restrict__ maskA) {
    int tid = threadIdx.x;
    int pglob = blockIdx.x * 256 + tid;   // 0..16383  (b*4096 + p)
    int oc = blockIdx.y;                  // 0..26
    int b = pglob >> 12;
    int p = pglob & 4095;
    int y = p >> 6, xx = p & 63;

    int idx9[9]; float fl9[9];
#pragma unroll
    for (int t = 0; t < 9; ++t) {
        int dy = t / 3 - 1, dx = t % 3 - 1;
        int yy = y + dy, xc = xx + dx;
        bool v = (yy >= 0 && yy < IMG_H && xc >= 0 && xc < IMG_W);
        idx9[t] = min(max(yy, 0), IMG_H - 1) * IMG_W + min(max(xc, 0), IMG_W - 1);
        fl9[t] = v ? 1.0f : 0.0f;
    }
    const float* xb = x + (size_t)b * (CIN * HWW);
    const float* wrow = w_off + oc * (CIN * 9);
    float acc = b_off[oc];
    for (int c = 0; c < CIN; ++c) {
        const float* plane = xb + c * HWW;
        const float* wc = wrow + c * 9;
#pragma unroll
        for (int t = 0; t < 9; ++t)
            acc += (wc[t] * fl9[t]) * plane[idx9[t]];
    }
    if (oc < 18) {
        int k = oc >> 1;
        float* dst = (oc & 1) ? offX : offY;
        dst[(b * 9 + k) * HWW + p] = acc;
    } else {
        maskA[(b * 9 + (oc - 18)) * HWW + p] = 1.0f / (1.0f + expf(-acc));
    }
}

// ---------------- Prep: w_dcn -> bf16 A-fragment order ----------------
// K order: ck' = (c>>5)*288 + kp*32 + (c&31)  (kp-major inside each 32-c chunk).
// Entry g = ((step*16 + octile)*64 + lane); holds 8 bf16: A[oc][k] with
// oc = octile*16 + (lane&15), k = step*32 + (lane>>4)*8 + j.
__global__ __launch_bounds__(256) void wprep(const float* __restrict__ w_dcn,
                                             short* __restrict__ wF) {
    int g = blockIdx.x * 256 + threadIdx.x;   // 72*16*64 = 73728
    int lane = g & 63;
    int rest = g >> 6;
    int octile = rest & 15;
    int step = rest >> 4;                     // 0..71
    int ch = step / 9, kp = step % 9;
    int oc = octile * 16 + (lane & 15);
    int cbase = ch * 32 + (lane >> 4) * 8;
    short8 v;
#pragma unroll
    for (int j = 0; j < 8; ++j)
        v[j] = f2bf(w_dcn[oc * 2304 + (cbase + j) * 9 + kp]);
    *(short8*)(wF + (size_t)g * 8) = v;
}

// ---------------- Main: fused bilinear-sample + MFMA implicit GEMM ----------------
// Block: 256 thr (4 waves), tile = 64 px (one image row) x 256 oc.
// Wave w: oc in [w*64, w*64+64). acc = 4(oc-sub) x 4(px-sub) of 16x16.
__global__ __launch_bounds__(256) void dcn_main(
        const float* __restrict__ x, const float* __restrict__ offY,
        const float* __restrict__ offX, const float* __restrict__ maskA,
        const short* __restrict__ wF, float* __restrict__ out) {
    __shared__ float4 preW[576];            // [kp][px] bilinear weights*mask*valid
    __shared__ int4  preI[576];             // [kp][px] 4 clamped gather indices
    __shared__ short Sm[64 * 296];          // [px][288 + 8 pad] bf16 sampled

    int tid = threadIdx.x;
    int blk = blockIdx.x;                   // 0..255
    int b = blk >> 6;
    int pbase = (blk & 63) * 64;            // row-aligned: one image row per block
    int yrow = pbase >> 6;
    const float* xb = x + (size_t)b * (CIN * HWW);

    // ---- per-block precompute of bilinear weights/indices (px, kp) ----
    for (int e = tid; e < 576; e += 256) {
        int px = e & 63, kp = e >> 6;
        int p = pbase + px;
        float oy = offY[(b * 9 + kp) * HWW + p];
        float ox = offX[(b * 9 + kp) * HWW + p];
        float m  = maskA[(b * 9 + kp) * HWW + p];
        float ys = (float)(yrow - 1 + kp / 3) + oy;
        float xs = (float)(px - 1 + kp % 3) + ox;
        float y0f = floorf(ys), x0f = floorf(xs);
        float fy = ys - y0f, fx = xs - x0f;
        int iy0 = (int)y0f, ix0 = (int)x0f;
        int iy1 = iy0 + 1, ix1 = ix0 + 1;
        float vy0 = (iy0 >= 0 && iy0 < IMG_H) ? 1.f : 0.f;
        float vy1 = (iy1 >= 0 && iy1 < IMG_H) ? 1.f : 0.f;
        float vx0 = (ix0 >= 0 && ix0 < IMG_W) ? 1.f : 0.f;
        float vx1 = (ix1 >= 0 && ix1 < IMG_W) ? 1.f : 0.f;
        int ry0 = min(max(iy0, 0), IMG_H - 1) * IMG_W;
        int ry1 = min(max(iy1, 0), IMG_H - 1) * IMG_W;
        int cx0 = min(max(ix0, 0), IMG_W - 1);
        int cx1 = min(max(ix1, 0), IMG_W - 1);
        float wy0 = 1.f - fy, wy1 = fy, wx0 = 1.f - fx, wx1 = fx;
        preW[e] = make_float4(wy0 * wx0 * vy0 * vx0 * m, wy0 * wx1 * vy0 * vx1 * m,
                              wy1 * wx0 * vy1 * vx0 * m, wy1 * wx1 * vy1 * vx1 * m);
        preI[e] = make_int4(ry0 + cx0, ry0 + cx1, ry1 + cx0, ry1 + cx1);
    }
    __syncthreads();

    int lane = tid & 63;
    int wave = tid >> 6;
    int fr = lane & 15, fq = lane >> 4;
    int spx = tid & 63, skg = tid >> 6;

    f32x4 acc[4][4];
#pragma unroll
    for (int m = 0; m < 4; ++m)
#pragma unroll
        for (int n = 0; n < 4; ++n)
            acc[m][n] = (f32x4){0.f, 0.f, 0.f, 0.f};

    for (int ch = 0; ch < 8; ++ch) {
        // ---- fill S: thread (spx, skg) samples 8 c-planes per kp ----
#pragma unroll
        for (int kp = 0; kp < 9; ++kp) {
            float4 wv = preW[kp * 64 + spx];
            int4  iv  = preI[kp * 64 + spx];
            const float* plane = xb + (size_t)(ch * 32 + skg * 8) * HWW;
            short8 sv;
#pragma unroll
            for (int i = 0; i < 8; ++i) {
                const float* pl = plane + (size_t)i * HWW;
                float v = wv.x * pl[iv.x] + wv.y * pl[iv.y] +
                          wv.z * pl[iv.z] + wv.w * pl[iv.w];
                sv[i] = f2bf(v);
            }
            *(short8*)&Sm[spx * 296 + kp * 32 + skg * 8] = sv;
        }
        __syncthreads();
        // ---- 9 MFMA K-steps over this chunk ----
#pragma unroll
        for (int kp = 0; kp < 9; ++kp) {
            int step = ch * 9 + kp;
            short8 aF[4];
#pragma unroll
            for (int m = 0; m < 4; ++m)
                aF[m] = *(const short8*)(wF +
                        ((size_t)(step * 16 + wave * 4 + m) * 64 + lane) * 8);
#pragma unroll
            for (int n = 0; n < 4; ++n) {
                short8 bF = *(const short8*)&Sm[(n * 16 + fr) * 296 + kp * 32 + fq * 8];
#pragma unroll
                for (int m = 0; m < 4; ++m)
                    acc[m][n] = __builtin_amdgcn_mfma_f32_16x16x32_bf16(
                            aF[m], bF, acc[m][n], 0, 0, 0);
            }
        }
        __syncthreads();
    }

    // ---- epilogue: D row = oc (fq*4+r), col = px (fr) ----
    float* outb = out + (size_t)b * (OUTC * HWW) + pbase;
#pragma unroll
    for (int m = 0; m < 4; ++m)
#pragma unroll
        for (int n = 0; n < 4; ++n)
#pragma unroll
            for (int r = 0; r < 4; ++r)
                outb[(size_t)(wave * 64 + m * 16 + fq * 4 + r) * HWW + n * 16 + fr] =
                        acc[m][n][r];
}

extern "C" void kernel_launch(void* const* d_in, const int* in_sizes, int n_in,
                              void* d_out, int out_size, void* d_ws, size_t ws_size,
                              hipStream_t stream) {
    const float* x     = (const float*)d_in[0];
    const float* w_off = (const float*)d_in[1];
    const float* b_off = (const float*)d_in[2];
    const float* w_dcn = (const float*)d_in[3];
    float* out = (float*)d_out;

    float* offY  = (float*)d_ws;            // 4*9*4096 floats
    float* offX  = offY + 4 * 9 * HWW;
    float* maskA = offX + 4 * 9 * HWW;
    short* wF    = (short*)(maskA + 4 * 9 * HWW);  // 2304*256 bf16

    offs_kernel<<<dim3(64, 27), 256, 0, stream>>>(x, w_off, b_off, offY, offX, maskA);
    wprep<<<288, 256, 0, stream>>>(w_dcn, wF);
    dcn_main<<<256, 256, 0, stream>>>(x, offY, offX, maskA, wF, out);
}

// Round 2
// 170.746 us; speedup vs baseline: 1.6927x; 1.6927x over previous
//
#include <hip/hip_runtime.h>

typedef __attribute__((ext_vector_type(8))) short short8;
typedef __attribute__((ext_vector_type(4))) short short4v;
typedef __attribute__((ext_vector_type(4))) float f32x4;

#define CIN 256
#define OUTC 256
#define HWW 4096
#define IMG_H 64
#define IMG_W 64

__device__ __forceinline__ short f2bf(float f) {
    unsigned u = __float_as_uint(f);
    u += 0x7fffu + ((u >> 16) & 1u);
    return (short)(u >> 16);
}

// ---------------- Prep: w_dcn -> bf16 A-fragment order ----------------
// Entry g = ((step*16 + octile)*64 + lane); holds 8 bf16: A[oc][k] with
// oc = octile*16 + (lane&15), k = step*32 + (lane>>4)*8 + j; step = ch*9+kp,
// c = ch*32 + (lane>>4)*8 + j.
__global__ __launch_bounds__(256) void wprep(const float* __restrict__ w_dcn,
                                             short* __restrict__ wF) {
    int g = blockIdx.x * 256 + threadIdx.x;   // 72*16*64 = 73728
    int lane = g & 63;
    int rest = g >> 6;
    int octile = rest & 15;
    int step = rest >> 4;                     // 0..71
    int ch = step / 9, kp = step % 9;
    int oc = octile * 16 + (lane & 15);
    int cbase = ch * 32 + (lane >> 4) * 8;
    short8 v;
#pragma unroll
    for (int j = 0; j < 8; ++j)
        v[j] = f2bf(w_dcn[oc * 2304 + (cbase + j) * 9 + kp]);
    *(short8*)(wF + (size_t)g * 8) = v;
}

// ---------------- Prep: w_off -> bf16 A-fragment order (oc padded to 32) ----
__global__ __launch_bounds__(256) void wprep_off(const float* __restrict__ w_off,
                                                 short* __restrict__ wFo) {
    int g = blockIdx.x * 256 + threadIdx.x;   // 72*2*64 = 9216
    int lane = g & 63;
    int rest = g >> 6;
    int octile = rest & 1;
    int step = rest >> 1;                     // 0..71
    int ch = step / 9, kp = step % 9;
    int oc = octile * 16 + (lane & 15);
    int cbase = ch * 32 + (lane >> 4) * 8;
    short8 v;
#pragma unroll
    for (int j = 0; j < 8; ++j)
        v[j] = (oc < 27) ? f2bf(w_off[(oc * 256 + cbase + j) * 9 + kp]) : (short)0;
    *(short8*)(wFo + (size_t)g * 8) = v;
}

// ---------------- Offset conv as MFMA implicit GEMM, K-split x2 ----------------
// Block (ks, b, row): 64 px (one image row) x 32 oc (27 used), K = 128 c x 9 taps.
// Writes partial P[ks][b][oc32][4096].
__global__ __launch_bounds__(256) void offs_mfma(
        const float* __restrict__ x, const short* __restrict__ wFo,
        float* __restrict__ P) {
    __shared__ short Sm[64 * 296];          // [px][288 + 8 pad] bf16 taps

    int tid = threadIdx.x;
    int blk = blockIdx.x;                   // 0..511
    int ks = blk >> 8;
    int b = (blk >> 6) & 3;
    int row = blk & 63;
    const float* xb = x + (size_t)b * (CIN * HWW);

    int spx = tid & 63, skg = tid >> 6;
    int lane = tid & 63, wave = tid >> 6;
    int fr = lane & 15, fq = lane >> 4;

    // per-thread tap geometry (spx fixed)
    int tIdx[9]; float tOk[9];
#pragma unroll
    for (int kp = 0; kp < 9; ++kp) {
        int yy = row - 1 + kp / 3;
        int xx = spx - 1 + kp % 3;
        bool ok = (yy >= 0 && yy < IMG_H && xx >= 0 && xx < IMG_W);
        tIdx[kp] = min(max(yy, 0), IMG_H - 1) * IMG_W + min(max(xx, 0), IMG_W - 1);
        tOk[kp] = ok ? 1.0f : 0.0f;
    }

    f32x4 acc[2];
    acc[0] = (f32x4){0.f, 0.f, 0.f, 0.f};
    acc[1] = (f32x4){0.f, 0.f, 0.f, 0.f};

    for (int chl = 0; chl < 4; ++chl) {
        int ch = ks * 4 + chl;              // global 32-c chunk index 0..7
        const float* pb = xb + (size_t)(ch * 32 + skg * 8) * HWW;
#pragma unroll
        for (int kp = 0; kp < 9; ++kp) {
            short8 sv;
#pragma unroll
            for (int i = 0; i < 8; ++i)
                sv[i] = f2bf(pb[(size_t)i * HWW + tIdx[kp]] * tOk[kp]);
            *(short8*)&Sm[spx * 296 + kp * 32 + skg * 8] = sv;
        }
        __syncthreads();
#pragma unroll
        for (int kp = 0; kp < 9; ++kp) {
            int step = ch * 9 + kp;
            short8 bF = *(const short8*)&Sm[(wave * 16 + fr) * 296 + kp * 32 + fq * 8];
#pragma unroll
            for (int m = 0; m < 2; ++m) {
                short8 aF = *(const short8*)(wFo +
                        ((size_t)(step * 2 + m) * 64 + lane) * 8);
                acc[m] = __builtin_amdgcn_mfma_f32_16x16x32_bf16(aF, bF, acc[m], 0, 0, 0);
            }
        }
        __syncthreads();
    }

    // D: row(oc) = m*16 + fq*4 + r, col(px) = wave*16 + fr
#pragma unroll
    for (int m = 0; m < 2; ++m)
#pragma unroll
        for (int r = 0; r < 4; ++r) {
            int oc = m * 16 + fq * 4 + r;
            if (oc < 27)
                P[(((size_t)ks * 4 + b) * 32 + oc) * HWW + row * 64 + wave * 16 + fr] =
                        acc[m][r];
        }
}

// ---------------- Main: fused bilinear-sample + MFMA implicit GEMM ----------------
// Block: 256 thr (4 waves), tile = 32 px x 256 oc.  512 blocks = 2/CU.
__global__ __launch_bounds__(256) void dcn_main(
        const float* __restrict__ x, const float* __restrict__ b_off,
        const float* __restrict__ P, const short* __restrict__ wF,
        float* __restrict__ out) {
    __shared__ float4 preW[288];            // [kp][px] bilinear weights*mask*valid
    __shared__ int4  preI[288];             // [kp][px] 4 clamped gather indices
    __shared__ short Sm[32 * 296];          // [px][288 + 8 pad] bf16 sampled

    int tid = threadIdx.x;
    int blk = blockIdx.x;                   // 0..511
    int b = blk >> 7;
    int ph = blk & 127;
    int pbase = ph * 32;
    int prow = pbase >> 6;
    int pc0 = pbase & 63;
    const float* xb = x + (size_t)b * (CIN * HWW);

    // ---- precompute bilinear weights/indices from offset-conv partials ----
    for (int e = tid; e < 288; e += 256) {
        int px = e & 31, kp = e >> 5;
        int p = pbase + px;
        const float* P0 = P + ((size_t)b * 32) * HWW + p;
        const float* P1 = P0 + (size_t)4 * 32 * HWW;
        float oy = P0[(size_t)(2 * kp) * HWW] + P1[(size_t)(2 * kp) * HWW] + b_off[2 * kp];
        float ox = P0[(size_t)(2 * kp + 1) * HWW] + P1[(size_t)(2 * kp + 1) * HWW] + b_off[2 * kp + 1];
        float ml = P0[(size_t)(18 + kp) * HWW] + P1[(size_t)(18 + kp) * HWW] + b_off[18 + kp];
        float m = 1.0f / (1.0f + expf(-ml));
        float ys = (float)(prow - 1 + kp / 3) + oy;
        float xs = (float)(pc0 + px - 1 + kp % 3) + ox;
        float y0f = floorf(ys), x0f = floorf(xs);
        float fy = ys - y0f, fx = xs - x0f;
        int iy0 = (int)y0f, ix0 = (int)x0f;
        int iy1 = iy0 + 1, ix1 = ix0 + 1;
        float vy0 = (iy0 >= 0 && iy0 < IMG_H) ? 1.f : 0.f;
        float vy1 = (iy1 >= 0 && iy1 < IMG_H) ? 1.f : 0.f;
        float vx0 = (ix0 >= 0 && ix0 < IMG_W) ? 1.f : 0.f;
        float vx1 = (ix1 >= 0 && ix1 < IMG_W) ? 1.f : 0.f;
        int ry0 = min(max(iy0, 0), IMG_H - 1) * IMG_W;
        int ry1 = min(max(iy1, 0), IMG_H - 1) * IMG_W;
        int cx0 = min(max(ix0, 0), IMG_W - 1);
        int cx1 = min(max(ix1, 0), IMG_W - 1);
        float wy0 = 1.f - fy, wy1 = fy, wx0 = 1.f - fx, wx1 = fx;
        preW[e] = make_float4(wy0 * wx0 * vy0 * vx0 * m, wy0 * wx1 * vy0 * vx1 * m,
                              wy1 * wx0 * vy1 * vx0 * m, wy1 * wx1 * vy1 * vx1 * m);
        preI[e] = make_int4(ry0 + cx0, ry0 + cx1, ry1 + cx0, ry1 + cx1);
    }
    __syncthreads();

    int lane = tid & 63;
    int wave = tid >> 6;
    int fr = lane & 15, fq = lane >> 4;
    int spx = tid & 31, skg = tid >> 5;     // fill: 8 groups x 4 channels

    f32x4 acc[4][2];
#pragma unroll
    for (int m = 0; m < 4; ++m)
#pragma unroll
        for (int n = 0; n < 2; ++n)
            acc[m][n] = (f32x4){0.f, 0.f, 0.f, 0.f};

    for (int ch = 0; ch < 8; ++ch) {
        // ---- fill S: thread (spx, skg) samples 4 c-planes per kp ----
        const float* plane = xb + (size_t)(ch * 32 + skg * 4) * HWW;
#pragma unroll
        for (int kp = 0; kp < 9; ++kp) {
            float4 wv = preW[kp * 32 + spx];
            int4  iv  = preI[kp * 32 + spx];
            short4v sv;
#pragma unroll
            for (int i = 0; i < 4; ++i) {
                const float* pl = plane + (size_t)i * HWW;
                float v = wv.x * pl[iv.x] + wv.y * pl[iv.y] +
                          wv.z * pl[iv.z] + wv.w * pl[iv.w];
                sv[i] = f2bf(v);
            }
            *(short4v*)&Sm[spx * 296 + kp * 32 + skg * 4] = sv;
        }
        __syncthreads();
        // ---- 9 MFMA K-steps over this chunk ----
#pragma unroll
        for (int kp = 0; kp < 9; ++kp) {
            int step = ch * 9 + kp;
            short8 aF[4];
#pragma unroll
            for (int m = 0; m < 4; ++m)
                aF[m] = *(const short8*)(wF +
                        ((size_t)(step * 16 + wave * 4 + m) * 64 + lane) * 8);
#pragma unroll
            for (int n = 0; n < 2; ++n) {
                short8 bF = *(const short8*)&Sm[(n * 16 + fr) * 296 + kp * 32 + fq * 8];
#pragma unroll
                for (int m = 0; m < 4; ++m)
                    acc[m][n] = __builtin_amdgcn_mfma_f32_16x16x32_bf16(
                            aF[m], bF, acc[m][n], 0, 0, 0);
            }
        }
        __syncthreads();
    }

    // ---- epilogue: D row = oc (fq*4+r), col = px (fr) ----
    float* outb = out + (size_t)b * (OUTC * HWW) + pbase;
#pragma unroll
    for (int m = 0; m < 4; ++m)
#pragma unroll
        for (int n = 0; n < 2; ++n)
#pragma unroll
            for (int r = 0; r < 4; ++r)
                outb[(size_t)(wave * 64 + m * 16 + fq * 4 + r) * HWW + n * 16 + fr] =
                        acc[m][n][r];
}

extern "C" void kernel_launch(void* const* d_in, const int* in_sizes, int n_in,
                              void* d_out, int out_size, void* d_ws, size_t ws_size,
                              hipStream_t stream) {
    const float* x     = (const float*)d_in[0];
    const float* w_off = (const float*)d_in[1];
    const float* b_off = (const float*)d_in[2];
    const float* w_dcn = (const float*)d_in[3];
    float* out = (float*)d_out;

    float* P   = (float*)d_ws;                      // 2*4*32*4096 f32 = 4.19 MB
    short* wF  = (short*)(P + 2 * 4 * 32 * HWW);    // 73728*8 bf16 = 1.18 MB
    short* wFo = wF + (size_t)73728 * 8;            // 9216*8 bf16 = 147 KB

    wprep<<<288, 256, 0, stream>>>(w_dcn, wF);
    wprep_off<<<36, 256, 0, stream>>>(w_off, wFo);
    offs_mfma<<<512, 256, 0, stream>>>(x, wFo, P);
    dcn_main<<<512, 256, 0, stream>>>(x, b_off, P, wF, out);
}

// Round 3
// 87.315 us; speedup vs baseline: 3.3102x; 1.9555x over previous
//
#include <hip/hip_runtime.h>

typedef __attribute__((ext_vector_type(8))) short short8;
typedef __attribute__((ext_vector_type(4))) float f32x4;

#define CIN 256
#define OUTC 256
#define HWW 4096
#define IMG_H 64
#define IMG_W 64
#define SROW 264   // LDS row stride in bf16 elems (256 + 8 pad)

__device__ __forceinline__ short f2bf(float f) {
    unsigned u = __float_as_uint(f);
    u += 0x7fffu + ((u >> 16) & 1u);
    return (short)(u >> 16);
}
__device__ __forceinline__ float bf2f(short s) {
    return __uint_as_float(((unsigned)(unsigned short)s) << 16);
}

// ---------------- x: NCHW f32 -> NHWC bf16 ----------------
__global__ __launch_bounds__(256) void xpose(const float* __restrict__ x,
                                             short* __restrict__ xT) {
    __shared__ float T[64][65];
    int p0 = blockIdx.x * 64;
    int c0 = blockIdx.y * 64;
    int b  = blockIdx.z;
    int j = threadIdx.x & 63, i = threadIdx.x >> 6;   // i 0..3
    const float* xb = x + ((size_t)b * CIN + c0) * HWW + p0;
#pragma unroll
    for (int k = 0; k < 16; ++k) {
        int row = i * 16 + k;
        T[row][j] = xb[(size_t)row * HWW + j];
    }
    __syncthreads();
    short* xTb = xT + ((size_t)b * HWW + p0) * CIN + c0;
#pragma unroll
    for (int k = 0; k < 16; ++k) {
        int prow = i * 16 + k;
        xTb[(size_t)prow * CIN + j] = f2bf(T[j][prow]);
    }
}

// ---------------- w_dcn -> bf16 A-frags, K order k = kp*256 + c ----------------
// g = ((step*16 + octile)*64 + lane)*8; step = kp*8+chv; oc = octile*16+(lane&15);
// c = chv*32 + (lane>>4)*8 + j.
__global__ __launch_bounds__(256) void wprep(const float* __restrict__ w_dcn,
                                             short* __restrict__ wF) {
    int g = blockIdx.x * 256 + threadIdx.x;   // 73728
    int lane = g & 63;
    int rest = g >> 6;
    int octile = rest & 15;
    int step = rest >> 4;                     // 0..71
    int kp = step >> 3, chv = step & 7;
    int oc = octile * 16 + (lane & 15);
    int cbase = chv * 32 + (lane >> 4) * 8;
    short8 v;
#pragma unroll
    for (int j = 0; j < 8; ++j)
        v[j] = f2bf(w_dcn[oc * 2304 + (cbase + j) * 9 + kp]);
    *(short8*)(wF + (size_t)g * 8) = v;
}

__global__ __launch_bounds__(256) void wprep_off(const float* __restrict__ w_off,
                                                 short* __restrict__ wFo) {
    int g = blockIdx.x * 256 + threadIdx.x;   // 9216
    int lane = g & 63;
    int rest = g >> 6;
    int octile = rest & 1;
    int step = rest >> 1;                     // 0..71
    int kp = step >> 3, chv = step & 7;
    int oc = octile * 16 + (lane & 15);
    int cbase = chv * 32 + (lane >> 4) * 8;
    short8 v;
#pragma unroll
    for (int j = 0; j < 8; ++j)
        v[j] = (oc < 27) ? f2bf(w_off[(oc * 256 + cbase + j) * 9 + kp]) : (short)0;
    *(short8*)(wFo + (size_t)g * 8) = v;
}

// ---------------- Offset conv: NHWC, kp-major, 32px x 32oc ----------------
__global__ __launch_bounds__(256) void offs_mfma(
        const short* __restrict__ xT, const short* __restrict__ wFo,
        float* __restrict__ P) {
    __shared__ short Sm[2][32 * SROW];

    int tid = threadIdx.x;
    int d = blockIdx.x;
    int L = (d & 7) * 64 + (d >> 3);        // XCD swizzle: 512 blocks
    int b = L >> 7;
    int ph = L & 127;
    int pbase = ph * 32;
    int prow = ph >> 1;
    int pc0 = (ph & 1) * 32;
    const short* xTb = xT + (size_t)b * HWW * CIN;

    int lane = tid & 63, wave = tid >> 6;
    int fr = lane & 15, fq = lane >> 4;
    int octile = wave & 1, pxt = wave >> 1;

    short8 st[4];

    auto loads = [&](int kp) {
        int yy = prow - 1 + kp / 3;
        int dx = kp % 3 - 1;
#pragma unroll
        for (int it = 0; it < 4; ++it) {
            int item = tid + it * 256;       // 0..1023
            int cg8 = item & 31, px = item >> 5;
            int xx = pc0 + px + dx;
            bool ok = (yy >= 0 && yy < IMG_H && xx >= 0 && xx < IMG_W);
            int idx = ok ? ((yy * IMG_W + xx) * CIN + cg8 * 8) : 0;
            short8 v = *(const short8*)&xTb[idx];
            if (!ok) v = (short8){0,0,0,0,0,0,0,0};
            st[it] = v;
        }
    };
    auto writes = [&](int bufi) {
#pragma unroll
        for (int it = 0; it < 4; ++it) {
            int item = tid + it * 256;
            int cg8 = item & 31, px = item >> 5;
            *(short8*)&Sm[bufi][px * SROW + cg8 * 8] = st[it];
        }
    };

    f32x4 acc = (f32x4){0.f, 0.f, 0.f, 0.f};

    loads(0); writes(0);
    __syncthreads();
    for (int kp = 0; kp < 9; ++kp) {
        if (kp < 8) loads(kp + 1);
        const short* SmB = Sm[kp & 1];
#pragma unroll
        for (int chv = 0; chv < 8; ++chv) {
            short8 aF = *(const short8*)(wFo +
                    (((size_t)((kp * 8 + chv) * 2 + octile)) * 64 + lane) * 8);
            short8 bF = *(const short8*)&SmB[(pxt * 16 + fr) * SROW + chv * 32 + fq * 8];
            acc = __builtin_amdgcn_mfma_f32_16x16x32_bf16(aF, bF, acc, 0, 0, 0);
        }
        if (kp < 8) writes((kp + 1) & 1);
        __syncthreads();
    }

#pragma unroll
    for (int r = 0; r < 4; ++r) {
        int oc = octile * 16 + fq * 4 + r;
        if (oc < 27)
            P[((size_t)b * 32 + oc) * HWW + pbase + pxt * 16 + fr] = acc[r];
    }
}

// ---------------- Main: NHWC sample + MFMA, 64px x 256oc, T14 pipeline ----------------
__global__ __launch_bounds__(512) void dcn_main(
        const short* __restrict__ xT, const float* __restrict__ b_off,
        const float* __restrict__ P, const short* __restrict__ wF,
        float* __restrict__ out) {
    __shared__ short Sm[2][64 * SROW];      // 67.6 KB
    __shared__ float4 preW[576];            // [kp][px]
    __shared__ int4  preI[576];             // [kp][px] elem offsets (idx*CIN)

    int tid = threadIdx.x;
    int d = blockIdx.x;
    int L = (d & 7) * 32 + (d >> 3);        // XCD swizzle: 256 blocks
    int b = L >> 6;
    int row = L & 63;
    int pbase = row * 64;
    const short* xTb = xT + (size_t)b * HWW * CIN;

    // ---- bilinear weights / indices from offset conv ----
    for (int e = tid; e < 576; e += 512) {
        int px = e & 63, kp = e >> 6;
        int p = pbase + px;
        float oy = P[((size_t)b * 32 + 2 * kp) * HWW + p] + b_off[2 * kp];
        float ox = P[((size_t)b * 32 + 2 * kp + 1) * HWW + p] + b_off[2 * kp + 1];
        float ml = P[((size_t)b * 32 + 18 + kp) * HWW + p] + b_off[18 + kp];
        float m = 1.0f / (1.0f + expf(-ml));
        float ys = (float)(row - 1 + kp / 3) + oy;
        float xs = (float)(px - 1 + kp % 3) + ox;
        float y0f = floorf(ys), x0f = floorf(xs);
        float fy = ys - y0f, fx = xs - x0f;
        int iy0 = (int)y0f, ix0 = (int)x0f;
        int iy1 = iy0 + 1, ix1 = ix0 + 1;
        float vy0 = (iy0 >= 0 && iy0 < IMG_H) ? 1.f : 0.f;
        float vy1 = (iy1 >= 0 && iy1 < IMG_H) ? 1.f : 0.f;
        float vx0 = (ix0 >= 0 && ix0 < IMG_W) ? 1.f : 0.f;
        float vx1 = (ix1 >= 0 && ix1 < IMG_W) ? 1.f : 0.f;
        int ry0 = min(max(iy0, 0), IMG_H - 1) * IMG_W;
        int ry1 = min(max(iy1, 0), IMG_H - 1) * IMG_W;
        int cx0 = min(max(ix0, 0), IMG_W - 1);
        int cx1 = min(max(ix1, 0), IMG_W - 1);
        float wy0 = 1.f - fy, wy1 = fy, wx0 = 1.f - fx, wx1 = fx;
        preW[e] = make_float4(wy0 * wx0 * vy0 * vx0 * m, wy0 * wx1 * vy0 * vx1 * m,
                              wy1 * wx0 * vy1 * vx0 * m, wy1 * wx1 * vy1 * vx1 * m);
        preI[e] = make_int4((ry0 + cx0) * CIN, (ry0 + cx1) * CIN,
                            (ry1 + cx0) * CIN, (ry1 + cx1) * CIN);
    }
    __syncthreads();

    int lane = tid & 63, wave = tid >> 6;
    int fr = lane & 15, fq = lane >> 4;
    int ocg = wave & 3, pxh = wave >> 2;

    short8 st[4][4];

    auto loads = [&](int kp) {
#pragma unroll
        for (int it = 0; it < 4; ++it) {
            int item = tid + it * 512;       // 0..2047
            int cg8 = item & 31, px = item >> 5;
            int4 iv = preI[kp * 64 + px];
            int co = cg8 * 8;
            st[it][0] = *(const short8*)&xTb[iv.x + co];
            st[it][1] = *(const short8*)&xTb[iv.y + co];
            st[it][2] = *(const short8*)&xTb[iv.z + co];
            st[it][3] = *(const short8*)&xTb[iv.w + co];
        }
    };
    auto writes = [&](int kp, int bufi) {
#pragma unroll
        for (int it = 0; it < 4; ++it) {
            int item = tid + it * 512;
            int cg8 = item & 31, px = item >> 5;
            float4 wv = preW[kp * 64 + px];
            short8 o;
#pragma unroll
            for (int j = 0; j < 8; ++j) {
                float v = wv.x * bf2f(st[it][0][j]) + wv.y * bf2f(st[it][1][j]) +
                          wv.z * bf2f(st[it][2][j]) + wv.w * bf2f(st[it][3][j]);
                o[j] = f2bf(v);
            }
            *(short8*)&Sm[bufi][px * SROW + cg8 * 8] = o;
        }
    };

    f32x4 acc[4][2];
#pragma unroll
    for (int m = 0; m < 4; ++m)
#pragma unroll
        for (int n = 0; n < 2; ++n)
            acc[m][n] = (f32x4){0.f, 0.f, 0.f, 0.f};

    loads(0); writes(0, 0);
    __syncthreads();
    for (int kp = 0; kp < 9; ++kp) {
        if (kp < 8) loads(kp + 1);
        const short* SmB = Sm[kp & 1];
#pragma unroll
        for (int chv = 0; chv < 8; ++chv) {
            short8 aF[4];
#pragma unroll
            for (int m = 0; m < 4; ++m)
                aF[m] = *(const short8*)(wF +
                        (((size_t)((kp * 8 + chv) * 16 + ocg * 4 + m)) * 64 + lane) * 8);
#pragma unroll
            for (int n = 0; n < 2; ++n) {
                short8 bF = *(const short8*)&SmB[(pxh * 32 + n * 16 + fr) * SROW +
                                                 chv * 32 + fq * 8];
#pragma unroll
                for (int m = 0; m < 4; ++m)
                    acc[m][n] = __builtin_amdgcn_mfma_f32_16x16x32_bf16(
                            aF[m], bF, acc[m][n], 0, 0, 0);
            }
        }
        if (kp < 8) writes(kp + 1, (kp + 1) & 1);
        __syncthreads();
    }

    float* outb = out + (size_t)b * (OUTC * HWW) + pbase;
#pragma unroll
    for (int m = 0; m < 4; ++m)
#pragma unroll
        for (int n = 0; n < 2; ++n)
#pragma unroll
            for (int r = 0; r < 4; ++r)
                outb[(size_t)(ocg * 64 + m * 16 + fq * 4 + r) * HWW +
                     pxh * 32 + n * 16 + fr] = acc[m][n][r];
}

extern "C" void kernel_launch(void* const* d_in, const int* in_sizes, int n_in,
                              void* d_out, int out_size, void* d_ws, size_t ws_size,
                              hipStream_t stream) {
    const float* x     = (const float*)d_in[0];
    const float* w_off = (const float*)d_in[1];
    const float* b_off = (const float*)d_in[2];
    const float* w_dcn = (const float*)d_in[3];
    float* out = (float*)d_out;

    short* xT  = (short*)d_ws;                       // 4*4096*256 bf16 = 8.4 MB
    float* P   = (float*)(xT + (size_t)4 * HWW * CIN);  // 4*32*4096 f32 = 2.1 MB
    short* wF  = (short*)(P + (size_t)4 * 32 * HWW); // 73728*8 bf16 = 1.18 MB
    short* wFo = wF + (size_t)73728 * 8;             // 9216*8 bf16 = 147 KB

    xpose<<<dim3(64, 4, 4), 256, 0, stream>>>(x, xT);
    wprep<<<288, 256, 0, stream>>>(w_dcn, wF);
    wprep_off<<<36, 256, 0, stream>>>(w_off, wFo);
    offs_mfma<<<512, 256, 0, stream>>>(xT, wFo, P);
    dcn_main<<<256, 512, 0, stream>>>(xT, b_off, P, wF, out);
}